// Round 1
// baseline (172.557 us; speedup 1.0000x reference)
//
#include <hip/hip_runtime.h>

// Problem constants (fixed by setup_inputs): B=4, C=3, H=W=512, window=5.
#define Bd   4
#define Cc   3
#define Hd   512
#define Wd   512
#define WIN  5
#define PAD  2

// Tile: 128 output cols x 8 output rows per block; 256 threads,
// each thread computes 4 consecutive w-pixels for all 3 channels.
#define TW   128
#define TH   8
#define LDS_COLS (TW + 2 * PAD)   // 132
#define LDS_ROWS (TH + 2 * PAD)   // 12

__global__ __launch_bounds__(256) void filter_layer_kernel(
    const float* __restrict__ x,   // [B,3,H,W]
    const float* __restrict__ f,   // [B,25,H,W]
    float* __restrict__ y)         // [B,3,H,W]
{
    __shared__ __align__(16) float xs[Cc][LDS_ROWS][LDS_COLS];  // 19,008 B

    const int b  = blockIdx.z;
    const int h0 = blockIdx.y * TH;
    const int w0 = blockIdx.x * TW;
    const int tid = threadIdx.x;

    // ---- Stage x tile (+halo) into LDS, zero-padded at image borders ----
    const int tile_n = Cc * LDS_ROWS * LDS_COLS;  // 4752 floats
    for (int idx = tid; idx < tile_n; idx += 256) {
        const int col = idx % LDS_COLS;
        const int t   = idx / LDS_COLS;
        const int row = t % LDS_ROWS;
        const int c   = t / LDS_ROWS;
        const int gh  = h0 + row - PAD;
        const int gw  = w0 + col - PAD;
        float v = 0.0f;
        if (gh >= 0 && gh < Hd && gw >= 0 && gw < Wd)
            v = x[(((size_t)b * Cc + c) * Hd + gh) * Wd + gw];
        xs[c][row][col] = v;
    }
    __syncthreads();

    // ---- Per-thread pixel group ----
    const int tx   = tid & 31;     // 32 groups across the 128-wide tile
    const int ty   = tid >> 5;     // 8 rows
    const int wloc = tx * 4;       // local col of first of 4 pixels
    const int h    = h0 + ty;
    const int gw   = w0 + wloc;

    float acc[Cc][4];
    #pragma unroll
    for (int c = 0; c < Cc; ++c)
        #pragma unroll
        for (int p = 0; p < 4; ++p) acc[c][p] = 0.0f;

    // f[b, k, h, gw .. gw+3]; k-plane stride = Hd*Wd floats
    const float* fb = f + ((size_t)b * (WIN * WIN)) * Hd * Wd
                        + (size_t)h * Wd + gw;

    #pragma unroll
    for (int i = 0; i < WIN; ++i) {
        // Preload the 8-float x row segment per channel (2x ds_read_b128).
        // lds col for output px p, tap j is wloc + p + j  (p+j in 0..7).
        float xr[Cc][8];
        #pragma unroll
        for (int c = 0; c < Cc; ++c) {
            const float4* src = (const float4*)&xs[c][ty + i][wloc];
            const float4 a = src[0];
            const float4 b4 = src[1];
            xr[c][0] = a.x;  xr[c][1] = a.y;  xr[c][2] = a.z;  xr[c][3] = a.w;
            xr[c][4] = b4.x; xr[c][5] = b4.y; xr[c][6] = b4.z; xr[c][7] = b4.w;
        }
        #pragma unroll
        for (int j = 0; j < WIN; ++j) {
            const int k = i * WIN + j;
            const float4 fv = *(const float4*)(fb + (size_t)k * Hd * Wd);
            #pragma unroll
            for (int c = 0; c < Cc; ++c) {
                acc[c][0] += fv.x * xr[c][j + 0];
                acc[c][1] += fv.y * xr[c][j + 1];
                acc[c][2] += fv.z * xr[c][j + 2];
                acc[c][3] += fv.w * xr[c][j + 3];
            }
        }
    }

    // ---- Store 3 channels x 4 pixels ----
    #pragma unroll
    for (int c = 0; c < Cc; ++c) {
        float4 o;
        o.x = acc[c][0]; o.y = acc[c][1]; o.z = acc[c][2]; o.w = acc[c][3];
        *(float4*)(y + (((size_t)b * Cc + c) * Hd + h) * Wd + gw) = o;
    }
}

extern "C" void kernel_launch(void* const* d_in, const int* in_sizes, int n_in,
                              void* d_out, int out_size, void* d_ws, size_t ws_size,
                              hipStream_t stream) {
    const float* x = (const float*)d_in[0];   // [4,3,512,512] fp32
    const float* f = (const float*)d_in[1];   // [4,25,512,512] fp32
    float* y = (float*)d_out;                 // [4,3,512,512] fp32

    dim3 grid(Wd / TW, Hd / TH, Bd);          // (4, 64, 4) = 1024 blocks
    filter_layer_kernel<<<grid, dim3(256), 0, stream>>>(x, f, y);
}

// Round 2
// 167.044 us; speedup vs baseline: 1.0330x; 1.0330x over previous
//
#include <hip/hip_runtime.h>

// Problem constants (fixed by setup_inputs): B=4, C=3, H=W=512, window=5.
#define Bd   4
#define Cc   3
#define Hd   512
#define Wd   512
#define WIN  5
#define PAD  2
#define PLANE (Hd * Wd)           // 262144 floats = 1 MiB per f tap-plane

// Tile: 128 output cols x 8 output rows per block; 256 threads,
// each thread computes 4 consecutive w-pixels for all 3 channels.
#define TW   128
#define TH   8
#define LDS_COLS (TW + 2 * PAD)   // 132
#define LDS_ROWS (TH + 2 * PAD)   // 12

// Plain vector type (NOT HIP's float4 class) so __builtin_nontemporal_load
// and aligned 16B loads work cleanly.
typedef float f4 __attribute__((ext_vector_type(4)));

// __launch_bounds__(256,4): cap VGPR<=128 -> >=4 waves/EU -> 4 blocks/CU
// (16 waves/CU). LDS 19008B*4 = 76KB < 160KB, so LDS is not the limiter.
__global__ __launch_bounds__(256, 4) void filter_layer_kernel(
    const float* __restrict__ x,   // [B,3,H,W]
    const float* __restrict__ f,   // [B,25,H,W]
    float* __restrict__ y)         // [B,3,H,W]
{
    __shared__ __align__(16) float xs[Cc][LDS_ROWS][LDS_COLS];  // 19,008 B

    const int b  = blockIdx.z;
    const int h0 = blockIdx.y * TH;
    const int w0 = blockIdx.x * TW;
    const int tid = threadIdx.x;

    // ---- Stage x tile (+halo) into LDS, zero-padded at image borders ----
    const int tile_n = Cc * LDS_ROWS * LDS_COLS;  // 4752 floats
    for (int idx = tid; idx < tile_n; idx += 256) {
        const int col = idx % LDS_COLS;
        const int t   = idx / LDS_COLS;
        const int row = t % LDS_ROWS;
        const int c   = t / LDS_ROWS;
        const int gh  = h0 + row - PAD;
        const int gw  = w0 + col - PAD;
        float v = 0.0f;
        if (gh >= 0 && gh < Hd && gw >= 0 && gw < Wd)
            v = x[(((size_t)b * Cc + c) * Hd + gh) * Wd + gw];
        xs[c][row][col] = v;
    }
    __syncthreads();

    // ---- Per-thread pixel group ----
    const int tx   = tid & 31;     // 32 groups across the 128-wide tile
    const int ty   = tid >> 5;     // 8 rows
    const int wloc = tx * 4;       // local col of first of 4 pixels
    const int h    = h0 + ty;
    const int gw   = w0 + wloc;

    // f[b, k, h, gw .. gw+3]; k-plane stride = PLANE floats
    const float* fb = f + ((size_t)b * (WIN * WIN)) * PLANE
                        + (size_t)h * Wd + gw;

    float acc[Cc][4];
    #pragma unroll
    for (int c = 0; c < Cc; ++c)
        #pragma unroll
        for (int p = 0; p < 4; ++p) acc[c][p] = 0.0f;

    // Rolling 5-deep prefetch: load tap-row i+1's five f float4s while
    // computing with tap-row i. Bounded live set (~90 VGPRs), 5 outstanding
    // 1KB wave-loads -> enough MLP to saturate HBM at 16 waves/CU.
    f4 fcur[WIN], fnxt[WIN];
    #pragma unroll
    for (int j = 0; j < WIN; ++j)
        fcur[j] = __builtin_nontemporal_load(
            (const f4*)(fb + (size_t)j * PLANE));

    #pragma unroll 1
    for (int i = 0; i < WIN; ++i) {
        if (i + 1 < WIN) {
            const float* fr = fb + (size_t)(i + 1) * WIN * PLANE;
            #pragma unroll
            for (int j = 0; j < WIN; ++j)
                fnxt[j] = __builtin_nontemporal_load(
                    (const f4*)(fr + (size_t)j * PLANE));
        }

        // Preload the 8-float x row segment per channel (2x ds_read_b128).
        // lds col for output px p, tap j is wloc + p + j  (p+j in 0..7).
        float xr[Cc][8];
        #pragma unroll
        for (int c = 0; c < Cc; ++c) {
            const f4* src = (const f4*)&xs[c][ty + i][wloc];
            const f4 a  = src[0];
            const f4 b4 = src[1];
            xr[c][0] = a.x;  xr[c][1] = a.y;  xr[c][2] = a.z;  xr[c][3] = a.w;
            xr[c][4] = b4.x; xr[c][5] = b4.y; xr[c][6] = b4.z; xr[c][7] = b4.w;
        }

        #pragma unroll
        for (int j = 0; j < WIN; ++j) {
            const f4 fv = fcur[j];
            #pragma unroll
            for (int c = 0; c < Cc; ++c) {
                acc[c][0] += fv.x * xr[c][j + 0];
                acc[c][1] += fv.y * xr[c][j + 1];
                acc[c][2] += fv.z * xr[c][j + 2];
                acc[c][3] += fv.w * xr[c][j + 3];
            }
        }

        #pragma unroll
        for (int j = 0; j < WIN; ++j) fcur[j] = fnxt[j];
    }

    // ---- Store 3 channels x 4 pixels ----
    #pragma unroll
    for (int c = 0; c < Cc; ++c) {
        f4 o;
        o.x = acc[c][0]; o.y = acc[c][1]; o.z = acc[c][2]; o.w = acc[c][3];
        *(f4*)(y + (((size_t)b * Cc + c) * Hd + h) * Wd + gw) = o;
    }
}

extern "C" void kernel_launch(void* const* d_in, const int* in_sizes, int n_in,
                              void* d_out, int out_size, void* d_ws, size_t ws_size,
                              hipStream_t stream) {
    const float* x = (const float*)d_in[0];   // [4,3,512,512] fp32
    const float* f = (const float*)d_in[1];   // [4,25,512,512] fp32
    float* y = (float*)d_out;                 // [4,3,512,512] fp32

    dim3 grid(Wd / TW, Hd / TH, Bd);          // (4, 64, 4) = 1024 blocks
    filter_layer_kernel<<<grid, dim3(256), 0, stream>>>(x, f, y);
}